// Round 1
// baseline (246.552 us; speedup 1.0000x reference)
//
#include <hip/hip_runtime.h>

// Problem constants (from reference)
#define BATCH 16384
#define DI 2048      // INPUT_DELAY_SIZE * INPUT_SIZE
#define DO 64        // OUTPUT_DELAY_SIZE * OUTPUT_SIZE
#define IS 64        // INPUT_SIZE

// One block of 256 threads per batch row.
// Each thread owns 8 contiguous itdl elements (2 x float4):
//   - accumulates iw-dot partial
//   - writes the shifted copy (k -> k-64) for k >= 64
//   - threads 0..7 instead append input[b][0:64] at the tail [1984,2048)
// Wave 0 (threads 0..63) additionally handles otdl (64 elems): ow-dot partial
// plus the shift-by-1 copy. Reduction: shuffle across 64 lanes -> LDS(4) -> t0.
__global__ __launch_bounds__(256) void arx_cell_kernel(
    const float* __restrict__ input,   // [B, 64]
    const float* __restrict__ itdl,    // [B, 2048]
    const float* __restrict__ otdl,    // [B, 64]
    const float* __restrict__ iw,      // [2048]
    const float* __restrict__ ow,      // [64]
    const float* __restrict__ bias,    // [1]
    float* __restrict__ out)           // [B] ++ [B*2048] ++ [B*64]
{
    const int b = blockIdx.x;
    const int t = threadIdx.x;

    const float* it = itdl + (size_t)b * DI;
    float* out0 = out;                              // outputs  [B]
    float* out1 = out + BATCH;                      // itdl_new [B, DI]
    float* out2 = out + BATCH + (size_t)BATCH * DI; // otdl_new [B, DO]

    // ---- itdl: load 8 elems, dot with iw ----
    const int k0 = t * 8;
    float4 v0 = *(const float4*)(it + k0);
    float4 v1 = *(const float4*)(it + k0 + 4);
    float4 w0 = *(const float4*)(iw + k0);
    float4 w1 = *(const float4*)(iw + k0 + 4);
    float partial = v0.x * w0.x + v0.y * w0.y + v0.z * w0.z + v0.w * w0.w
                  + v1.x * w1.x + v1.y * w1.y + v1.z * w1.z + v1.w * w1.w;

    // ---- otdl: wave 0 only (64 elems) ----
    float oval = 0.0f;
    if (t < DO) {
        oval = otdl[(size_t)b * DO + t];
        partial += oval * ow[t];
    }

    // ---- itdl_new: shift-by-64 copy, reusing registers ----
    float* o1 = out1 + (size_t)b * DI;
    if (k0 >= IS) {
        *(float4*)(o1 + (k0 - IS))     = v0;
        *(float4*)(o1 + (k0 - IS) + 4) = v1;
    } else {
        // threads 0..7 append input[b][0:64] at tail [DI-IS, DI)
        const float* in = input + (size_t)b * IS;
        float4 i0 = *(const float4*)(in + k0);
        float4 i1 = *(const float4*)(in + k0 + 4);
        *(float4*)(o1 + (DI - IS) + k0)     = i0;
        *(float4*)(o1 + (DI - IS) + k0 + 4) = i1;
    }

    // ---- otdl_new: shift-by-1 copy (positions 0..62) ----
    if (t >= 1 && t < DO) {
        out2[(size_t)b * DO + (t - 1)] = oval;
    }

    // ---- reduce partial across the block ----
    #pragma unroll
    for (int off = 32; off > 0; off >>= 1)
        partial += __shfl_down(partial, off, 64);

    __shared__ float sred[4];
    if ((t & 63) == 0) sred[t >> 6] = partial;
    __syncthreads();

    if (t == 0) {
        float a2 = sred[0] + sred[1] + sred[2] + sred[3] + bias[0];
        out0[b] = a2;                           // outputs[b]
        out2[(size_t)b * DO + (DO - 1)] = a2;   // otdl_new tail
    }
}

extern "C" void kernel_launch(void* const* d_in, const int* in_sizes, int n_in,
                              void* d_out, int out_size, void* d_ws, size_t ws_size,
                              hipStream_t stream) {
    const float* input = (const float*)d_in[0];
    const float* itdl  = (const float*)d_in[1];
    const float* otdl  = (const float*)d_in[2];
    const float* iw    = (const float*)d_in[3];
    const float* ow    = (const float*)d_in[4];
    const float* bias  = (const float*)d_in[5];
    float* out = (float*)d_out;

    arx_cell_kernel<<<BATCH, 256, 0, stream>>>(input, itdl, otdl, iw, ow, bias, out);
}